// Round 4
// baseline (233.210 us; speedup 1.0000x reference)
//
#include <hip/hip_runtime.h>

#define NN 50000
#define NP 50048  // padded to multiple of 64
#define NE 800000
#define ET (NE + NN)
#define NB 196              // coarse buckets (dst>>8)
#define CAP 8192            // per-bucket capacity (avg 4337, +58 sigma)
#define EPB 4096            // edges per p1 block (4 per thread)
#define P1_B ((ET + EPB - 1) / EPB)   // 208
#define CONVW_B 32                    // 32768 / 1024
#define CONVX_B (NP * 32 / 1024)      // 1564 (exact)
#define FRONT_B (P1_B + CONVW_B + CONVX_B)
#define GEMM_B (NP / 64)              // 782
#define MID_B (NB + GEMM_B)           // 978
#define AGG1_BPH 3125                 // blocks per head; 16 dst/block; 3125*16 = 50000 exact

typedef __attribute__((ext_vector_type(8))) short short8;
typedef __attribute__((ext_vector_type(4))) float f32x4;

static __device__ __forceinline__ float bf2f(unsigned short u) {
  union { unsigned int i; float f; } v; v.i = ((unsigned int)u) << 16; return v.f;
}
static __device__ __forceinline__ unsigned short f2bf(float f) {
  union { unsigned int i; float f; } v; v.f = f;
  unsigned int r = v.i + 0x7fffu + ((v.i >> 16) & 1u);
  return (unsigned short)(r >> 16);
}
static __device__ __forceinline__ float lrelu(float z) { return z > 0.f ? z : 0.2f * z; }

// ---------------- fused front (1024 thr): p1 (CSR bucket, 4 edges/thread) | conv_w | conv_x ----------------
__global__ __launch_bounds__(1024) void k_front(
    const int* __restrict__ ei, int* __restrict__ gcount, int* __restrict__ tmp,
    const float* __restrict__ W1, unsigned short* __restrict__ wh,
    const float* __restrict__ x, unsigned short* __restrict__ xh) {
  __shared__ int hist[NB];
  __shared__ int lbase[NB];
  const int b = blockIdx.x;
  const int tid = threadIdx.x;
  if (b < P1_B) {
    if (tid < NB) hist[tid] = 0;
    __syncthreads();
    const int e0 = b * EPB + tid;
    int bkv[4], locv[4], pkv[4];
    bool val[4];
#pragma unroll
    for (int j = 0; j < 4; ++j) {
      int e = e0 + j * 1024;
      val[j] = (e < ET);
      int s = 0, d = 0;
      if (val[j]) {
        s = (e < NE) ? ei[e] : (e - NE);
        d = (e < NE) ? ei[NE + e] : (e - NE);
      }
      bkv[j] = d >> 8;
      pkv[j] = (s << 8) | (d & 255);
      locv[j] = val[j] ? atomicAdd(&hist[bkv[j]], 1) : 0;  // LDS atomic
    }
    __syncthreads();
    if (tid < NB) {
      int c = hist[tid];
      lbase[tid] = (c > 0) ? atomicAdd(&gcount[tid], c) : 0;
    }
    __syncthreads();
#pragma unroll
    for (int j = 0; j < 4; ++j)
      if (val[j]) tmp[bkv[j] * CAP + lbase[bkv[j]] + locv[j]] = pkv[j];
  } else if (b < P1_B + CONVW_B) {
    int i = (b - P1_B) * 1024 + tid;  // i < 32768
    int k = i >> 8, n = i & 255;
    wh[n * 128 + k] = f2bf(W1[i]);
  } else {
    int i4 = (b - P1_B - CONVW_B) * 1024 + tid;  // i4 < NP*32 exactly
    int i = i4 * 4;
    int row = i >> 7;
    float4 v = (row < NN) ? *(const float4*)(x + i) : (float4){0.f, 0.f, 0.f, 0.f};
    ushort4 h;
    h.x = f2bf(v.x);
    h.y = f2bf(v.y);
    h.z = f2bf(v.z);
    h.w = f2bf(v.w);
    *(ushort4*)(xh + i) = h;
  }
}

// ---------------- fused mid (256 thr): p2 (counting sort) | gemm1 (bf16 MFMA) ----------------
// h1 stored HEAD-MAJOR: h1h[head][node][32] bf16 (3.2 MB per head -> fits one XCD L2).
// as1/ad1 stored head-major [head][node].
__global__ __launch_bounds__(256) void k_mid(
    const int* __restrict__ tmp, const int* __restrict__ gcount,
    int* __restrict__ ssrc, int* __restrict__ row_ptr,
    const unsigned short* __restrict__ xh, const unsigned short* __restrict__ wh,
    const float* __restrict__ a1s, const float* __restrict__ a1d,
    unsigned short* __restrict__ h1, float* __restrict__ as1, float* __restrict__ ad1) {
  __shared__ unsigned short hst[64][264];  // 33792 B; p2 path aliases into it
  const int tid = threadIdx.x;
  if (blockIdx.x < NB) {
    int* hist = (int*)&hst[0][0];
    int* sa = hist + 256;
    int* sb = sa + 256;
    int* cur = sb + 256;
    int* base_sh = cur + 256;
    const int t = tid;
    const int b = blockIdx.x;
    const int n_b = gcount[b];
    sa[t] = (t < NB) ? gcount[t] : 0;
    __syncthreads();
    {
      int* s = sa;
      int* d = sb;
      for (int off = 1; off < 256; off <<= 1) {
        int v = s[t];
        if (t >= off) v += s[t - off];
        d[t] = v;
        int* tm = s; s = d; d = tm;
        __syncthreads();
      }
      if (t == 0) {
        base_sh[0] = (b == 0) ? 0 : s[b - 1];
        if (b == 0) row_ptr[NN] = ET;
      }
    }
    hist[t] = 0;
    __syncthreads();
    const int base = base_sh[0];
    for (int i = t; i < n_b; i += 256) {
      int p = tmp[b * CAP + i];
      atomicAdd(&hist[p & 255], 1);
    }
    __syncthreads();
    sa[t] = hist[t];
    __syncthreads();
    {
      int* s = sa;
      int* d = sb;
      for (int off = 1; off < 256; off <<= 1) {
        int v = s[t];
        if (t >= off) v += s[t - off];
        d[t] = v;
        int* tm = s; s = d; d = tm;
        __syncthreads();
      }
      int excl = (t == 0) ? 0 : s[t - 1];
      int start = base + excl;
      cur[t] = start;
      int d_glob = (b << 8) + t;
      if (d_glob < NN) row_ptr[d_glob] = start;
    }
    __syncthreads();
    for (int i = t; i < n_b; i += 256) {
      int p = tmp[b * CAP + i];
      int pos = atomicAdd(&cur[p & 255], 1);  // LDS cursor
      ssrc[pos] = p >> 8;
    }
    return;
  }
  // ---- gemm1: single-pass bf16 MFMA ----
  const int gb = blockIdx.x - NB;
  const int w = tid >> 6, lane = tid & 63;
  const int quad = lane >> 4, m16 = lane & 15;
  const int row0 = gb * 64;
  const int koff = quad * 8;

  f32x4 acc[4][4];
  for (int mt = 0; mt < 4; ++mt)
    for (int nt = 0; nt < 4; ++nt) acc[mt][nt] = (f32x4){0.f, 0.f, 0.f, 0.f};

  for (int kt = 0; kt < 4; ++kt) {
    short8 ah[4], bh[4];
    for (int mt = 0; mt < 4; ++mt) {
      size_t ra = (size_t)(row0 + mt * 16 + m16) * 128 + kt * 32 + koff;
      ah[mt] = *(const short8*)(xh + ra);
    }
    for (int nt = 0; nt < 4; ++nt) {
      size_t rb = (size_t)(w * 64 + nt * 16 + m16) * 128 + kt * 32 + koff;
      bh[nt] = *(const short8*)(wh + rb);
    }
    for (int mt = 0; mt < 4; ++mt)
      for (int nt = 0; nt < 4; ++nt)
        acc[mt][nt] = __builtin_amdgcn_mfma_f32_16x16x32_bf16(ah[mt], bh[nt], acc[mt][nt], 0, 0, 0);
  }
  for (int mt = 0; mt < 4; ++mt)
    for (int nt = 0; nt < 4; ++nt) {
      int c = w * 64 + nt * 16 + m16;
      int rb = mt * 16 + quad * 4;
      for (int r = 0; r < 4; ++r) hst[rb + r][c] = f2bf(acc[mt][nt][r]);
    }
  __syncthreads();
  for (int p = 0; p < 8; ++p) {
    int idx = p * 256 + tid;
    int row = idx >> 5, u4 = idx & 31;
    int grow = row0 + row;
    if (grow < NN) {
      uint4 v = *(const uint4*)&hst[row][u4 * 8];
      int head = u4 >> 2, cg = u4 & 3;  // col = u4*8; head = col>>5; in-head col = (u4&3)*8
      *(uint4*)(h1 + ((size_t)head * NN + grow) * 32 + cg * 8) = v;
    }
  }
  for (int p = 0; p < 2; ++p) {
    int id = p * 256 + tid;
    int row = id >> 3, head = id & 7;
    int grow = row0 + row;
    if (grow < NN) {
      float sa = 0.f, sd = 0.f;
      for (int c = 0; c < 32; ++c) {
        float hv = bf2f(hst[row][head * 32 + c]);
        sa = fmaf(hv, a1s[head * 32 + c], sa);
        sd = fmaf(hv, a1d[head * 32 + c], sd);
      }
      as1[(size_t)head * NN + grow] = sa;
      ad1[(size_t)head * NN + grow] = sd;
    }
  }
}

// ---------------- Layer-1 aggregation: head-per-XCD, 4 lanes/edge (64B-coalesced row gather) ----------------
// R3 lesson: latency pipelining was null -> bound by L1/TA TRANSACTION throughput (~1/cy/CU):
// lane-per-edge issues 4 row-load instrs whose 64 lanes hit 64 distinct lines = 4 trans/edge.
// Fix: 4 chunk-lanes per edge load consecutive 16B of the SAME 64B row -> TA merges to 1 trans/edge.
// Wave = 4 groups x (4 edge-slots x 4 chunk-lanes); 16-lane group owns one (dst,head).
// head = blockIdx.x & 7 -> XCD pinning (proven: FETCH 220->31 MB). Block covers 16 dsts;
// 3125 blocks/head x 16 = 50000 exact (no bounds check). acc = 8 floats/lane (low VGPR).
__global__ __launch_bounds__(256) void k_agg1(
    const int* __restrict__ row_ptr, const int* __restrict__ ssrc,
    const unsigned short* __restrict__ h1h, const float* __restrict__ as1h,
    const float* __restrict__ ad1h, const float* __restrict__ b1,
    const float* __restrict__ W2, float* __restrict__ ndf) {
  const int head = blockIdx.x & 7;
  const int bg = blockIdx.x >> 3;            // 0..3124
  const int lane = threadIdx.x & 63;
  const int wid = threadIdx.x >> 6;
  const int g = lane >> 4;                   // group 0..3 within wave
  const int slot = (lane >> 2) & 3;          // edge slot 0..3
  const int chunk = lane & 3;                // 16B chunk of the 64B row
  const int dst = bg * 16 + wid * 4 + g;     // exact cover of [0, 50000)

  const unsigned short* __restrict__ ht = h1h + (size_t)head * NN * 32;
  const float* __restrict__ ast = as1h + (size_t)head * NN;
  const float adh = ad1h[(size_t)head * NN + dst];

  const int start = row_ptr[dst], end = row_ptr[dst + 1];

  float acc[8];
#pragma unroll
  for (int i = 0; i < 8; ++i) acc[i] = 0.f;
  float wsum = 0.f;

  for (int e = start + slot; e < end; e += 4) {
    int s = ssrc[e];                                   // 4-dup across chunk lanes -> coalesced
    float w = __expf(lrelu(ast[s] + adh));
    wsum += w;
    uint4 q = *(const uint4*)(ht + (size_t)s * 32 + chunk * 8);  // 4 lanes = one 64B line
    acc[0] = fmaf(w, bf2f((unsigned short)(q.x & 0xffffu)), acc[0]);
    acc[1] = fmaf(w, bf2f((unsigned short)(q.x >> 16)), acc[1]);
    acc[2] = fmaf(w, bf2f((unsigned short)(q.y & 0xffffu)), acc[2]);
    acc[3] = fmaf(w, bf2f((unsigned short)(q.y >> 16)), acc[3]);
    acc[4] = fmaf(w, bf2f((unsigned short)(q.z & 0xffffu)), acc[4]);
    acc[5] = fmaf(w, bf2f((unsigned short)(q.z >> 16)), acc[5]);
    acc[6] = fmaf(w, bf2f((unsigned short)(q.w & 0xffffu)), acc[6]);
    acc[7] = fmaf(w, bf2f((unsigned short)(q.w >> 16)), acc[7]);
  }

  // reduce across the 4 edge slots (lane bits 2,3); chunk-lanes keep their 8 channels
  wsum += __shfl_xor(wsum, 4);
  wsum += __shfl_xor(wsum, 8);
#pragma unroll
  for (int i = 0; i < 8; ++i) {
    acc[i] += __shfl_xor(acc[i], 4);
    acc[i] += __shfl_xor(acc[i], 8);
  }
  const float inv_s = 1.f / (wsum + 1e-16f);

  // epilogue: channels head*32 + chunk*8 + j
  float tp0 = 0.f, tp1 = 0.f;
#pragma unroll
  for (int j = 0; j < 8; ++j) {
    int ch = head * 32 + chunk * 8 + j;
    float vv = fmaf(acc[j], inv_s, b1[ch]);
    vv = vv > 0.f ? vv : (__expf(vv) - 1.f);  // ELU
    tp0 = fmaf(vv, W2[ch * 2 + 0], tp0);
    tp1 = fmaf(vv, W2[ch * 2 + 1], tp1);
  }
  // reduce across the 4 chunk lanes (lane bits 0,1)
  tp0 += __shfl_xor(tp0, 1); tp1 += __shfl_xor(tp1, 1);
  tp0 += __shfl_xor(tp0, 2); tp1 += __shfl_xor(tp1, 2);
  if ((lane & 15) == 0) {
    atomicAdd(ndf + (size_t)dst * 2 + 0, tp0);
    atomicAdd(ndf + (size_t)dst * 2 + 1, tp1);
  }
}

// ---------------- Layer-2 aggregation: 8 lanes per dst; nd is float2 (tp0,tp1) ----------------
__global__ __launch_bounds__(256) void k_agg2(
    const int* __restrict__ row_ptr, const int* __restrict__ ssrc,
    const float2* __restrict__ nd, const float* __restrict__ a2s,
    const float* __restrict__ a2d, const float* __restrict__ b2,
    float* __restrict__ out) {
  int gid = blockIdx.x * 256 + threadIdx.x;
  int n = gid >> 3;
  int l8 = threadIdx.x & 7;
  if (n >= NN) return;
  int st = row_ptr[n], en = row_ptr[n + 1];
  float2 td = nd[n];
  const float s0 = a2s[0], s1 = a2s[1];
  float dv = td.x * a2d[0] + td.y * a2d[1];
  float ssum = 0.f, o0 = 0.f, o1 = 0.f;
  for (int e = st + l8; e < en; e += 8) {
    int s = ssrc[e];
    float2 v = nd[s];
    float zv = fmaf(v.x, s0, v.y * s1);
    float w = __expf(lrelu(zv + dv));
    ssum += w;
    o0 = fmaf(w, v.x, o0);
    o1 = fmaf(w, v.y, o1);
  }
  ssum += __shfl_xor(ssum, 1); o0 += __shfl_xor(o0, 1); o1 += __shfl_xor(o1, 1);
  ssum += __shfl_xor(ssum, 2); o0 += __shfl_xor(o0, 2); o1 += __shfl_xor(o1, 2);
  ssum += __shfl_xor(ssum, 4); o0 += __shfl_xor(o0, 4); o1 += __shfl_xor(o1, 4);
  if (l8 == 0) {
    float inv = 1.f / (ssum + 1e-16f);
    out[(size_t)n * 2 + 0] = o0 * inv + b2[0];
    out[(size_t)n * 2 + 1] = o1 * inv + b2[1];
  }
}

extern "C" void kernel_launch(void* const* d_in, const int* in_sizes, int n_in,
                              void* d_out, int out_size, void* d_ws, size_t ws_size,
                              hipStream_t stream) {
  const float* x = (const float*)d_in[0];
  const int* ei = (const int*)d_in[1];
  // d_in[2] = batch (unused)
  const float* W1 = (const float*)d_in[3];
  const float* a1s = (const float*)d_in[4];
  const float* a1d = (const float*)d_in[5];
  const float* b1 = (const float*)d_in[6];
  const float* W2 = (const float*)d_in[7];
  const float* a2s = (const float*)d_in[8];
  const float* a2d = (const float*)d_in[9];
  const float* b2 = (const float*)d_in[10];
  float* out = (float*)d_out;

  char* ws = (char*)d_ws;
  size_t off = 0;
  auto alloc = [&](size_t bytes) -> void* {
    void* p = ws + off;
    off += (bytes + 255) & ~(size_t)255;
    return p;
  };
  int* gcount = (int*)alloc((size_t)NB * 4);
  int* tmp = (int*)alloc((size_t)NB * CAP * 4);
  int* row_ptr = (int*)alloc((size_t)(NN + 1) * 4);
  int* ssrc = (int*)alloc((size_t)ET * 4);
  unsigned short* xh = (unsigned short*)alloc((size_t)NP * 128 * 2);
  unsigned short* wh = (unsigned short*)alloc((size_t)32768 * 2);
  unsigned short* h1 = (unsigned short*)alloc((size_t)NN * 256 * 2);  // head-major [8][NN][32]
  float* as1 = (float*)alloc((size_t)NN * 8 * 4);                     // head-major [8][NN]
  float* ad1 = (float*)alloc((size_t)NN * 8 * 4);                     // head-major [8][NN]
  float* ndf = (float*)alloc((size_t)NN * 8);                         // float2 per node (tp0,tp1)
  (void)ws_size; (void)in_sizes; (void)n_in; (void)out_size;

  hipMemsetAsync(gcount, 0, (size_t)NB * 4, stream);
  hipMemsetAsync(ndf, 0, (size_t)NN * 8, stream);
  k_front<<<FRONT_B, 1024, 0, stream>>>(ei, gcount, tmp, W1, wh, x, xh);
  k_mid<<<MID_B, 256, 0, stream>>>(tmp, gcount, ssrc, row_ptr, xh, wh, a1s, a1d, h1, as1, ad1);
  k_agg1<<<8 * AGG1_BPH, 256, 0, stream>>>(row_ptr, ssrc, h1, as1, ad1, b1, W2, ndf);
  k_agg2<<<(NN * 8 + 255) / 256, 256, 0, stream>>>(row_ptr, ssrc, (const float2*)ndf, a2s, a2d, b2, out);
}

// Round 5
// 213.770 us; speedup vs baseline: 1.0909x; 1.0909x over previous
//
#include <hip/hip_runtime.h>

#define NN 50000
#define NP 50048  // padded to multiple of 64
#define NE 800000
#define ET (NE + NN)
#define NB 196              // coarse buckets (dst>>8)
#define CAP 8192            // per-bucket capacity (avg 4337, +58 sigma)
#define EPB 4096            // edges per p1 block (4 per thread)
#define P1_B ((ET + EPB - 1) / EPB)   // 208
#define CONVW_B 32                    // 32768 / 1024
#define CONVX_B 391                   // NP*32/4096 (4 float4 per thread, exact)
#define FRONT_B (P1_B + CONVW_B + CONVX_B)
#define GEMM_B (NP / 64)              // 782
#define MID_B (NB + GEMM_B)           // 978
#define AGG1_B 2048                   // persistent blocks; 8192 waves grid-stride dsts

typedef __attribute__((ext_vector_type(8))) short short8;
typedef __attribute__((ext_vector_type(4))) float f32x4;

static __device__ __forceinline__ float bf2f(unsigned short u) {
  union { unsigned int i; float f; } v; v.i = ((unsigned int)u) << 16; return v.f;
}
static __device__ __forceinline__ unsigned short f2bf(float f) {
  union { unsigned int i; float f; } v; v.f = f;
  unsigned int r = v.i + 0x7fffu + ((v.i >> 16) & 1u);
  return (unsigned short)(r >> 16);
}
static __device__ __forceinline__ float lrelu(float z) { return z > 0.f ? z : 0.2f * z; }

// ---------------- fused front (1024 thr): p1 (CSR bucket, 4 edges/thread) | conv_w | conv_x ----------------
__global__ __launch_bounds__(1024) void k_front(
    const int* __restrict__ ei, int* __restrict__ gcount, int* __restrict__ tmp,
    const float* __restrict__ W1, unsigned short* __restrict__ wh,
    const float* __restrict__ x, unsigned short* __restrict__ xh) {
  __shared__ int hist[NB];
  __shared__ int lbase[NB];
  const int b = blockIdx.x;
  const int tid = threadIdx.x;
  if (b < P1_B) {
    if (tid < NB) hist[tid] = 0;
    __syncthreads();
    const int e0 = b * EPB + tid;
    int bkv[4], locv[4], pkv[4];
    bool val[4];
#pragma unroll
    for (int j = 0; j < 4; ++j) {
      int e = e0 + j * 1024;
      val[j] = (e < ET);
      int s = 0, d = 0;
      if (val[j]) {
        s = (e < NE) ? ei[e] : (e - NE);
        d = (e < NE) ? ei[NE + e] : (e - NE);
      }
      bkv[j] = d >> 8;
      pkv[j] = (s << 8) | (d & 255);
      locv[j] = val[j] ? atomicAdd(&hist[bkv[j]], 1) : 0;  // LDS atomic
    }
    __syncthreads();
    if (tid < NB) {
      int c = hist[tid];
      lbase[tid] = (c > 0) ? atomicAdd(&gcount[tid], c) : 0;
    }
    __syncthreads();
#pragma unroll
    for (int j = 0; j < 4; ++j)
      if (val[j]) tmp[bkv[j] * CAP + lbase[bkv[j]] + locv[j]] = pkv[j];
  } else if (b < P1_B + CONVW_B) {
    int i = (b - P1_B) * 1024 + tid;  // i < 32768
    int k = i >> 8, n = i & 255;
    wh[n * 128 + k] = f2bf(W1[i]);
  } else {
    int base = (b - P1_B - CONVW_B) * 4096 + tid;  // 4096 float4-items per block
#pragma unroll
    for (int k = 0; k < 4; ++k) {
      int i4 = base + k * 1024;  // < NP*32 exactly (391*4096 = NP*32)
      int i = i4 * 4;
      int row = i >> 7;
      float4 v = (row < NN) ? *(const float4*)(x + i) : (float4){0.f, 0.f, 0.f, 0.f};
      ushort4 h;
      h.x = f2bf(v.x);
      h.y = f2bf(v.y);
      h.z = f2bf(v.z);
      h.w = f2bf(v.w);
      *(ushort4*)(xh + i) = h;
    }
  }
}

// ---------------- fused mid (256 thr): p2 (counting sort) | gemm1 (bf16 MFMA) ----------------
// h1 node-major [node][256] (line-optimal for the all-heads gather in agg1).
__global__ __launch_bounds__(256) void k_mid(
    const int* __restrict__ tmp, const int* __restrict__ gcount,
    int* __restrict__ ssrc, int* __restrict__ row_ptr,
    const unsigned short* __restrict__ xh, const unsigned short* __restrict__ wh,
    const float* __restrict__ a1s, const float* __restrict__ a1d,
    unsigned short* __restrict__ h1, float* __restrict__ as1, float* __restrict__ ad1) {
  __shared__ unsigned short hst[64][264];  // 33792 B; p2 path aliases into it
  const int tid = threadIdx.x;
  if (blockIdx.x < NB) {
    int* hist = (int*)&hst[0][0];
    int* sa = hist + 256;
    int* sb = sa + 256;
    int* cur = sb + 256;
    int* base_sh = cur + 256;
    const int t = tid;
    const int b = blockIdx.x;
    const int n_b = gcount[b];
    sa[t] = (t < NB) ? gcount[t] : 0;
    __syncthreads();
    {
      int* s = sa;
      int* d = sb;
      for (int off = 1; off < 256; off <<= 1) {
        int v = s[t];
        if (t >= off) v += s[t - off];
        d[t] = v;
        int* tm = s; s = d; d = tm;
        __syncthreads();
      }
      if (t == 0) {
        base_sh[0] = (b == 0) ? 0 : s[b - 1];
        if (b == 0) row_ptr[NN] = ET;
      }
    }
    hist[t] = 0;
    __syncthreads();
    const int base = base_sh[0];
    for (int i = t; i < n_b; i += 256) {
      int p = tmp[b * CAP + i];
      atomicAdd(&hist[p & 255], 1);
    }
    __syncthreads();
    sa[t] = hist[t];
    __syncthreads();
    {
      int* s = sa;
      int* d = sb;
      for (int off = 1; off < 256; off <<= 1) {
        int v = s[t];
        if (t >= off) v += s[t - off];
        d[t] = v;
        int* tm = s; s = d; d = tm;
        __syncthreads();
      }
      int excl = (t == 0) ? 0 : s[t - 1];
      int start = base + excl;
      cur[t] = start;
      int d_glob = (b << 8) + t;
      if (d_glob < NN) row_ptr[d_glob] = start;
    }
    __syncthreads();
    for (int i = t; i < n_b; i += 256) {
      int p = tmp[b * CAP + i];
      int pos = atomicAdd(&cur[p & 255], 1);  // LDS cursor
      ssrc[pos] = p >> 8;
    }
    return;
  }
  // ---- gemm1: single-pass bf16 MFMA ----
  const int gb = blockIdx.x - NB;
  const int w = tid >> 6, lane = tid & 63;
  const int quad = lane >> 4, m16 = lane & 15;
  const int row0 = gb * 64;
  const int koff = quad * 8;

  f32x4 acc[4][4];
  for (int mt = 0; mt < 4; ++mt)
    for (int nt = 0; nt < 4; ++nt) acc[mt][nt] = (f32x4){0.f, 0.f, 0.f, 0.f};

  for (int kt = 0; kt < 4; ++kt) {
    short8 ah[4], bh[4];
    for (int mt = 0; mt < 4; ++mt) {
      size_t ra = (size_t)(row0 + mt * 16 + m16) * 128 + kt * 32 + koff;
      ah[mt] = *(const short8*)(xh + ra);
    }
    for (int nt = 0; nt < 4; ++nt) {
      size_t rb = (size_t)(w * 64 + nt * 16 + m16) * 128 + kt * 32 + koff;
      bh[nt] = *(const short8*)(wh + rb);
    }
    for (int mt = 0; mt < 4; ++mt)
      for (int nt = 0; nt < 4; ++nt)
        acc[mt][nt] = __builtin_amdgcn_mfma_f32_16x16x32_bf16(ah[mt], bh[nt], acc[mt][nt], 0, 0, 0);
  }
  for (int mt = 0; mt < 4; ++mt)
    for (int nt = 0; nt < 4; ++nt) {
      int c = w * 64 + nt * 16 + m16;
      int rb = mt * 16 + quad * 4;
      for (int r = 0; r < 4; ++r) hst[rb + r][c] = f2bf(acc[mt][nt][r]);
    }
  __syncthreads();
  for (int p = 0; p < 8; ++p) {
    int idx = p * 256 + tid;
    int row = idx >> 5, u4 = idx & 31;
    int grow = row0 + row;
    if (grow < NN) {
      uint4 v = *(const uint4*)&hst[row][u4 * 8];
      *(uint4*)(h1 + (size_t)grow * 256 + u4 * 8) = v;
    }
  }
  for (int p = 0; p < 2; ++p) {
    int id = p * 256 + tid;
    int row = id >> 3, head = id & 7;
    int grow = row0 + row;
    if (grow < NN) {
      float sa = 0.f, sd = 0.f;
      for (int c = 0; c < 32; ++c) {
        float hv = bf2f(hst[row][head * 32 + c]);
        sa = fmaf(hv, a1s[head * 32 + c], sa);
        sd = fmaf(hv, a1d[head * 32 + c], sd);
      }
      as1[(size_t)grow * 8 + head] = sa;
      ad1[(size_t)grow * 8 + head] = sd;
    }
  }
}

// ---------------- Layer-1 aggregation: R0 proven form (70us, L3-path rooflined), persistent grid ----------------
// Node-major h1: per edge the wave reads the full 512B row (8 heads) in 8 lines = 1 line per
// (edge,head) -- line-optimal; head-split variants (R1-R4) were 4-8x worse on per-task overhead.
// Persistent 2048-block grid-stride removes the 12500-block dispatch churn (R0 showed 61% occupancy
// at 36 VGPR / 0 LDS -- dispatch rate is the only remaining limiter candidate; this tests it).
__global__ __launch_bounds__(256) void k_agg1(
    const int* __restrict__ row_ptr, const int* __restrict__ ssrc,
    const unsigned short* __restrict__ h1, const float* __restrict__ as1,
    const float* __restrict__ ad1, const float* __restrict__ b1,
    const float* __restrict__ W2, const float* __restrict__ a2s,
    const float* __restrict__ a2d, float4* __restrict__ nd) {
  const int lane = threadIdx.x & 63;
  const int hA = lane & 7;
  const int eoff = lane >> 3;
  const int hB = lane >> 3;
  const int cB = (lane & 7) * 4;
  for (int dst = (int)(blockIdx.x * 4 + (threadIdx.x >> 6)); dst < NN; dst += AGG1_B * 4) {
    const int start = row_ptr[dst], end = row_ptr[dst + 1];
    const float ad_h = ad1[(size_t)dst * 8 + hA];
    float s_loc = 0.f;
    float acc0 = 0.f, acc1 = 0.f, acc2 = 0.f, acc3 = 0.f;
    for (int base = start; base < end; base += 16) {
      int ea = base + eoff, eb = base + 8 + eoff;
      int sa_ = 0, sb_ = 0;
      float wa = 0.f, wb = 0.f;
      if (ea < end) {
        sa_ = ssrc[ea];
        wa = __expf(lrelu(as1[(size_t)sa_ * 8 + hA] + ad_h));
      }
      if (eb < end) {
        sb_ = ssrc[eb];
        wb = __expf(lrelu(as1[(size_t)sb_ * 8 + hA] + ad_h));
      }
      s_loc += wa + wb;
      uint2 u[16];
      float w16[16];
#pragma unroll
      for (int j = 0; j < 8; ++j) {
        int se = __shfl(sa_, j * 8);
        w16[j] = __shfl(wa, j * 8 + hB);
        u[j] = *(const uint2*)(h1 + (size_t)se * 256 + hB * 32 + cB);
      }
#pragma unroll
      for (int j = 0; j < 8; ++j) {
        int se = __shfl(sb_, j * 8);
        w16[8 + j] = __shfl(wb, j * 8 + hB);
        u[8 + j] = *(const uint2*)(h1 + (size_t)se * 256 + hB * 32 + cB);
      }
#pragma unroll
      for (int j = 0; j < 16; ++j) {
        float w = w16[j];
        acc0 = fmaf(w, bf2f((unsigned short)(u[j].x & 0xffffu)), acc0);
        acc1 = fmaf(w, bf2f((unsigned short)(u[j].x >> 16)), acc1);
        acc2 = fmaf(w, bf2f((unsigned short)(u[j].y & 0xffffu)), acc2);
        acc3 = fmaf(w, bf2f((unsigned short)(u[j].y >> 16)), acc3);
      }
    }
    float s_red = s_loc;
    s_red += __shfl_xor(s_red, 8);
    s_red += __shfl_xor(s_red, 16);
    s_red += __shfl_xor(s_red, 32);
    const float inv_s = 1.f / (s_red + 1e-16f);
    const float inv_sB = __shfl(inv_s, hB);  // lane hB holds s for head hB (its hA == hB)
    float a0 = acc0 * inv_sB, a1 = acc1 * inv_sB, a2 = acc2 * inv_sB, a3 = acc3 * inv_sB;
    const int col = hB * 32 + cB;
    float av[4] = {a0, a1, a2, a3};
    float tp0 = 0.f, tp1 = 0.f;
    for (int j = 0; j < 4; ++j) {
      float v = av[j] + b1[col + j];
      v = v > 0.f ? v : (__expf(v) - 1.f);  // ELU
      tp0 = fmaf(v, W2[(col + j) * 2 + 0], tp0);
      tp1 = fmaf(v, W2[(col + j) * 2 + 1], tp1);
    }
    for (int off = 32; off >= 1; off >>= 1) {
      tp0 += __shfl_xor(tp0, off);
      tp1 += __shfl_xor(tp1, off);
    }
    if (lane == 0) {
      float s2v = tp0 * a2s[0] + tp1 * a2s[1];
      float d2v = tp0 * a2d[0] + tp1 * a2d[1];
      nd[dst] = (float4){tp0, tp1, s2v, d2v};  // packed node table for agg2
    }
  }
}

// ---------------- Layer-2 aggregation: 8 lanes per dst, packed float4 gathers (r16 proven form) ----------------
__global__ __launch_bounds__(256) void k_agg2(
    const int* __restrict__ row_ptr, const int* __restrict__ ssrc,
    const float4* __restrict__ nd, const float* __restrict__ b2,
    float* __restrict__ out) {
  int gid = blockIdx.x * 256 + threadIdx.x;
  int n = gid >> 3;
  int l8 = threadIdx.x & 7;
  if (n >= NN) return;
  int st = row_ptr[n], en = row_ptr[n + 1];
  float dv = nd[n].w;
  float ssum = 0.f, o0 = 0.f, o1 = 0.f;
  for (int e = st + l8; e < en; e += 8) {
    int s = ssrc[e];
    float4 v = nd[s];
    float w = __expf(lrelu(v.z + dv));
    ssum += w;
    o0 = fmaf(w, v.x, o0);
    o1 = fmaf(w, v.y, o1);
  }
  ssum += __shfl_xor(ssum, 1); o0 += __shfl_xor(o0, 1); o1 += __shfl_xor(o1, 1);
  ssum += __shfl_xor(ssum, 2); o0 += __shfl_xor(o0, 2); o1 += __shfl_xor(o1, 2);
  ssum += __shfl_xor(ssum, 4); o0 += __shfl_xor(o0, 4); o1 += __shfl_xor(o1, 4);
  if (l8 == 0) {
    float inv = 1.f / (ssum + 1e-16f);
    out[(size_t)n * 2 + 0] = o0 * inv + b2[0];
    out[(size_t)n * 2 + 1] = o1 * inv + b2[1];
  }
}

extern "C" void kernel_launch(void* const* d_in, const int* in_sizes, int n_in,
                              void* d_out, int out_size, void* d_ws, size_t ws_size,
                              hipStream_t stream) {
  const float* x = (const float*)d_in[0];
  const int* ei = (const int*)d_in[1];
  // d_in[2] = batch (unused)
  const float* W1 = (const float*)d_in[3];
  const float* a1s = (const float*)d_in[4];
  const float* a1d = (const float*)d_in[5];
  const float* b1 = (const float*)d_in[6];
  const float* W2 = (const float*)d_in[7];
  const float* a2s = (const float*)d_in[8];
  const float* a2d = (const float*)d_in[9];
  const float* b2 = (const float*)d_in[10];
  float* out = (float*)d_out;

  char* ws = (char*)d_ws;
  size_t off = 0;
  auto alloc = [&](size_t bytes) -> void* {
    void* p = ws + off;
    off += (bytes + 255) & ~(size_t)255;
    return p;
  };
  int* gcount = (int*)alloc((size_t)NB * 4);
  int* tmp = (int*)alloc((size_t)NB * CAP * 4);
  int* row_ptr = (int*)alloc((size_t)(NN + 1) * 4);
  int* ssrc = (int*)alloc((size_t)ET * 4);
  unsigned short* xh = (unsigned short*)alloc((size_t)NP * 128 * 2);
  unsigned short* wh = (unsigned short*)alloc((size_t)32768 * 2);
  unsigned short* h1 = (unsigned short*)alloc((size_t)NN * 256 * 2);  // node-major [NN][256]
  float* as1 = (float*)alloc((size_t)NN * 8 * 4);                     // node-major [NN][8]
  float* ad1 = (float*)alloc((size_t)NN * 8 * 4);                     // node-major [NN][8]
  float4* nd = (float4*)alloc((size_t)NN * 16);
  (void)ws_size; (void)in_sizes; (void)n_in; (void)out_size;

  hipMemsetAsync(gcount, 0, (size_t)NB * 4, stream);
  k_front<<<FRONT_B, 1024, 0, stream>>>(ei, gcount, tmp, W1, wh, x, xh);
  k_mid<<<MID_B, 256, 0, stream>>>(tmp, gcount, ssrc, row_ptr, xh, wh, a1s, a1d, h1, as1, ad1);
  k_agg1<<<AGG1_B, 256, 0, stream>>>(row_ptr, ssrc, h1, as1, ad1, b1, W2, a2s, a2d, nd);
  k_agg2<<<(NN * 8 + 255) / 256, 256, 0, stream>>>(row_ptr, ssrc, nd, b2, out);
}